// Round 2
// baseline (14962.309 us; speedup 1.0000x reference)
//
#include <hip/hip_runtime.h>

#define N_NODES 100000
#define N_EDGES 3200000
#define N_IN    128
#define N_OUT   64
#define ITERS   150
#define LEAK    0.01f

#define SCAN_CHUNK 1024
#define SCAN_NBLK  98   // 98*1024 = 100352 >= N_NODES+1
#define MAXB 1024       // max barrier slots

__device__ __forceinline__ float mml(float v) {
    v = (v < 0.0f) ? v * LEAK : v;
    if (v > 0.5f) v = 1.0f - 0.25f / v;
    return v;
}

__global__ void k_binit(const float* __restrict__ biases, float* __restrict__ b_in) {
    int i = blockIdx.x * blockDim.x + threadIdx.x;
    if (i < N_NODES) b_in[i] = biases[i];
}

// node_in.at[in_indices].set(in_w * x) -> last-write-wins for duplicates
__global__ void k_scatter_in(const float* __restrict__ x,
                             const float* __restrict__ in_w,
                             const int*   __restrict__ in_idx,
                             const float* __restrict__ biases,
                             float* __restrict__ b_in) {
    int k = threadIdx.x;
    if (k < N_IN) {
        int idx = in_idx[k];
        bool last = true;
        for (int j = k + 1; j < N_IN; ++j)
            if (in_idx[j] == idx) { last = false; break; }
        if (last) b_in[idx] = biases[idx] + in_w[k] * x[k];
    }
}

// y0 = act(0 + b_in)   (first reference iteration: A @ 0 == 0)
__global__ void k_y0(const float* __restrict__ b_in, float* __restrict__ y0) {
    int i = blockIdx.x * blockDim.x + threadIdx.x;
    if (i < N_NODES) y0[i] = mml(b_in[i]);
}

__global__ void k_hist(const int* __restrict__ rows, int* __restrict__ counts) {
    int i = blockIdx.x * blockDim.x + threadIdx.x;
    int stride = gridDim.x * blockDim.x;
    for (; i < N_EDGES; i += stride) atomicAdd(&counts[rows[i]], 1);
}

__global__ void k_scan1(const int* __restrict__ counts, int* __restrict__ rp,
                        int* __restrict__ blockSums) {
    __shared__ int sm[SCAN_CHUNK];
    int t = threadIdx.x;
    int i = blockIdx.x * SCAN_CHUNK + t;
    int v = (i < N_NODES) ? counts[i] : 0;
    sm[t] = v;
    __syncthreads();
    for (int off = 1; off < SCAN_CHUNK; off <<= 1) {
        int add = (t >= off) ? sm[t - off] : 0;
        __syncthreads();
        sm[t] += add;
        __syncthreads();
    }
    if (i <= N_NODES) rp[i] = sm[t] - v;
    if (t == SCAN_CHUNK - 1) blockSums[blockIdx.x] = sm[t];
}

__global__ void k_scan2(int* __restrict__ blockSums) {
    __shared__ int sm[128];
    int t = threadIdx.x;
    int v = (t < SCAN_NBLK) ? blockSums[t] : 0;
    sm[t] = v;
    __syncthreads();
    for (int off = 1; off < 128; off <<= 1) {
        int add = (t >= off) ? sm[t - off] : 0;
        __syncthreads();
        sm[t] += add;
        __syncthreads();
    }
    if (t < SCAN_NBLK) blockSums[t] = sm[t] - v;
}

__global__ void k_scan3(int* __restrict__ rp, const int* __restrict__ blockSums,
                        int* __restrict__ next) {
    int i = blockIdx.x * SCAN_CHUNK + threadIdx.x;
    if (i <= N_NODES) {
        int val = rp[i] + blockSums[blockIdx.x];
        rp[i] = val;
        if (i < N_NODES) next[i] = val;
    }
}

__global__ void k_scatter_edges(const int* __restrict__ rows, const int* __restrict__ cols,
                                const float* __restrict__ w,
                                int* __restrict__ next, int2* __restrict__ csr) {
    int i = blockIdx.x * blockDim.x + threadIdx.x;
    int stride = gridDim.x * blockDim.x;
    for (; i < N_EDGES; i += stride) {
        int r = rows[i];
        int p = atomicAdd(&next[r], 1);
        csr[p] = make_int2(cols[i], __float_as_int(w[i]));
    }
}

// Persistent main loop with a custom scalable barrier:
//  - arrival = per-block slot STORE (no same-line RMW serialization)
//  - poll = parallel loads of all slots + __syncthreads_and
//  - convergence bit rides in chg[it&1][b]; monotonic arrival counters
//    guarantee a block is never >1 iteration ahead, so the parity slot a
//    polling block reads is never overwritten mid-read.
__global__ __launch_bounds__(1024, 8) void k_iterate(
    const int*  __restrict__ rp,
    const int2* __restrict__ csr,
    const float* __restrict__ b_in,
    float* __restrict__ ybuf0,
    float* __restrict__ ybuf1,
    int* __restrict__ arr,      // MAXB arrival counters
    int* __restrict__ chg,      // 2*MAXB changed flags
    const int* __restrict__ out_idx,
    const float* __restrict__ out_w,
    float* __restrict__ out)
{
    const int nb = gridDim.x, b = blockIdx.x;
    const int t = threadIdx.x;
    const int g = t >> 2, j = t & 3;            // 4 lanes per row
    const int GROUPS = blockDim.x >> 2;
    const int row_beg = (int)((long long)b       * N_NODES / nb);
    const int row_end = (int)((long long)(b + 1) * N_NODES / nb);

    const float* ycur = ybuf0;
    float* ynext = ybuf1;

    for (int it = 1; it < ITERS; ++it) {
        int changed = 0;
        for (int row = row_beg + g; row < row_end; row += GROUPS) {
            const int beg = rp[row];
            const int end = rp[row + 1];
            float a0 = 0.f, a1 = 0.f;
            int e = beg + j;
            for (; e + 4 < end; e += 8) {        // lane-strided, 2-way MLP
                int2 c0 = csr[e];
                int2 c1 = csr[e + 4];
                a0 += __int_as_float(c0.y) * ycur[c0.x];
                a1 += __int_as_float(c1.y) * ycur[c1.x];
            }
            if (e < end) {
                int2 c = csr[e];
                a0 += __int_as_float(c.y) * ycur[c.x];
            }
            float a = a0 + a1;
            a += __shfl_xor(a, 1);
            a += __shfl_xor(a, 2);
            if (j == 0) {
                float v = mml(b_in[row] + a);
                changed |= (__float_as_int(v) != __float_as_int(ycur[row]));
                ynext[row] = v;
            }
        }
        int blockChanged = __syncthreads_or(changed);

        // ---- barrier: arrive ----
        if (t == 0) {
            __hip_atomic_store(&chg[(it & 1) * MAXB + b], blockChanged,
                               __ATOMIC_RELAXED, __HIP_MEMORY_SCOPE_AGENT);
            __builtin_amdgcn_fence(__ATOMIC_RELEASE, "agent"); // wb L2: ynext visible
            __hip_atomic_store(&arr[b], it,
                               __ATOMIC_RELAXED, __HIP_MEMORY_SCOPE_AGENT);
        }
        // ---- barrier: wait (parallel poll, no RMW) ----
        int ok;
        do {
            ok = (t < nb) ? (__hip_atomic_load(&arr[t], __ATOMIC_RELAXED,
                                __HIP_MEMORY_SCOPE_AGENT) >= it) : 1;
        } while (!__syncthreads_and(ok));
        __builtin_amdgcn_fence(__ATOMIC_ACQUIRE, "agent");     // inv: fresh y reads
        int c = (t < nb) ? __hip_atomic_load(&chg[(it & 1) * MAXB + t],
                             __ATOMIC_RELAXED, __HIP_MEMORY_SCOPE_AGENT) : 0;
        int anyChg = __syncthreads_or(c);

        { const float* tmp = ycur; ycur = ynext; ynext = (float*)tmp; }
        if (!anyChg) break;   // bitwise fixed point, uniform across all blocks
    }

    if (b == 0 && t < N_OUT) out[t] = out_w[t] * ycur[out_idx[t]];
}

extern "C" void kernel_launch(void* const* d_in, const int* in_sizes, int n_in,
                              void* d_out, int out_size, void* d_ws, size_t ws_size,
                              hipStream_t stream) {
    const float* x      = (const float*)d_in[0];
    const float* in_w   = (const float*)d_in[1];
    const float* rec_w  = (const float*)d_in[2];
    const float* biases = (const float*)d_in[3];
    const float* out_w  = (const float*)d_in[4];
    const int*   in_idx = (const int*)d_in[5];
    const int*   e_rows = (const int*)d_in[6];
    const int*   e_cols = (const int*)d_in[7];
    const int*   out_idx= (const int*)d_in[8];
    float* out = (float*)d_out;

    char* ws = (char*)d_ws;
    float* b_in    = (float*)ws;                    // N
    float* y0      = b_in + N_NODES;                // N
    float* y1      = y0 + N_NODES;                  // N
    int*   row_ptr = (int*)(y1 + N_NODES);          // N+1 (+pad)
    int*   next    = row_ptr + (N_NODES + 64);      // N
    int*   counts  = next + N_NODES;                // N
    int*   blockSums = counts + N_NODES;            // 128
    int*   arr     = blockSums + 128;               // MAXB
    int*   chg     = arr + MAXB;                    // 2*MAXB
    size_t off = (size_t)((char*)(chg + 2 * MAXB) - ws);
    off = (off + 15) & ~(size_t)15;
    int2* csr = (int2*)(ws + off);                  // N_EDGES int2 (25.6 MB)

    hipMemsetAsync(counts, 0, N_NODES * sizeof(int), stream);
    hipMemsetAsync(arr, 0, 3 * MAXB * sizeof(int), stream);   // arr + chg

    k_binit<<<391, 256, 0, stream>>>(biases, b_in);
    k_scatter_in<<<1, 128, 0, stream>>>(x, in_w, in_idx, biases, b_in);
    k_y0<<<391, 256, 0, stream>>>(b_in, y0);

    k_hist<<<1024, 256, 0, stream>>>(e_rows, counts);
    k_scan1<<<SCAN_NBLK, SCAN_CHUNK, 0, stream>>>(counts, row_ptr, blockSums);
    k_scan2<<<1, 128, 0, stream>>>(blockSums);
    k_scan3<<<SCAN_NBLK, SCAN_CHUNK, 0, stream>>>(row_ptr, blockSums, next);
    k_scatter_edges<<<1024, 256, 0, stream>>>(e_rows, e_cols, rec_w, next, csr);

    // grid = co-resident capacity (custom barrier requires co-residency)
    int mab = 0, ncu = 256, dev = 0;
    hipGetDevice(&dev);
    hipDeviceGetAttribute(&ncu, hipDeviceAttributeMultiprocessorCount, dev);
    hipOccupancyMaxActiveBlocksPerMultiprocessor(&mab, (const void*)k_iterate, 1024, 0);
    if (mab < 1) mab = 1;
    int nb = mab * ncu;
    if (nb > MAXB) nb = MAXB;

    int*   rp_a   = row_ptr;
    int2*  csr_a  = csr;
    float* bin_a  = b_in;
    float* y0_a   = y0;
    float* y1_a   = y1;
    int*   arr_a  = arr;
    int*   chg_a  = chg;
    const int*   oidx_a = out_idx;
    const float* ow_a   = out_w;
    float* out_a  = out;
    void* args[] = { &rp_a, &csr_a, &bin_a, &y0_a, &y1_a, &arr_a, &chg_a,
                     &oidx_a, &ow_a, &out_a };
    hipLaunchCooperativeKernel((void*)k_iterate, dim3(nb), dim3(1024),
                               args, 0, stream);
}

// Round 3
// 7843.630 us; speedup vs baseline: 1.9076x; 1.9076x over previous
//
#include <hip/hip_runtime.h>

#define N_NODES 100000
#define N_EDGES 3200000
#define N_IN    128
#define N_OUT   64
#define ITERS   150
#define LEAK    0.01f

#define NB      256            // 1 block per CU (forced by 100KB LDS)
#define NT      1024
#define RPB     391            // ceil(N_NODES / NB) rows per block
#define NQ      4              // column quarters
#define QSZ     25000          // columns per quarter (100KB of y in LDS)
#define NKEYS   (N_NODES * NQ) // (row, quarter) buckets
#define SCAN_CHUNK 1024
#define SCAN_NBLK  391         // 391*1024 >= NKEYS+1
#define NEPOCH  64
#define EPOCH_STRIDE 32        // ints -> 128B between epoch copies

__device__ __forceinline__ float mml(float v) {
    v = (v < 0.0f) ? v * LEAK : v;
    if (v > 0.5f) v = 1.0f - 0.25f / v;
    return v;
}

__global__ void k_binit(const float* __restrict__ biases, float* __restrict__ b_in) {
    int i = blockIdx.x * blockDim.x + threadIdx.x;
    if (i < N_NODES) b_in[i] = biases[i];
}

// node_in.at[in_indices].set(in_w * x) -> last-write-wins for duplicates
__global__ void k_scatter_in(const float* __restrict__ x,
                             const float* __restrict__ in_w,
                             const int*   __restrict__ in_idx,
                             const float* __restrict__ biases,
                             float* __restrict__ b_in) {
    int k = threadIdx.x;
    if (k < N_IN) {
        int idx = in_idx[k];
        bool last = true;
        for (int j = k + 1; j < N_IN; ++j)
            if (in_idx[j] == idx) { last = false; break; }
        if (last) b_in[idx] = biases[idx] + in_w[k] * x[k];
    }
}

// y0 = act(0 + b_in)   (first reference iteration: A @ 0 == 0)
__global__ void k_y0(const float* __restrict__ b_in, float* __restrict__ y0) {
    int i = blockIdx.x * blockDim.x + threadIdx.x;
    if (i < N_NODES) y0[i] = mml(b_in[i]);
}

// histogram over (row, col-quarter) buckets
__global__ void k_hist(const int* __restrict__ rows, const int* __restrict__ cols,
                       int* __restrict__ counts) {
    int i = blockIdx.x * blockDim.x + threadIdx.x;
    int stride = gridDim.x * blockDim.x;
    for (; i < N_EDGES; i += stride) {
        int key = rows[i] * NQ + cols[i] / QSZ;
        atomicAdd(&counts[key], 1);
    }
}

__global__ void k_scan1(const int* __restrict__ counts, int* __restrict__ rp,
                        int* __restrict__ blockSums) {
    __shared__ int sm[SCAN_CHUNK];
    int t = threadIdx.x;
    int i = blockIdx.x * SCAN_CHUNK + t;
    int v = (i < NKEYS) ? counts[i] : 0;
    sm[t] = v;
    __syncthreads();
    for (int off = 1; off < SCAN_CHUNK; off <<= 1) {
        int add = (t >= off) ? sm[t - off] : 0;
        __syncthreads();
        sm[t] += add;
        __syncthreads();
    }
    if (i <= NKEYS) rp[i] = sm[t] - v;
    if (t == SCAN_CHUNK - 1) blockSums[blockIdx.x] = sm[t];
}

__global__ void k_scan2(int* __restrict__ blockSums) {
    __shared__ int sm[512];
    int t = threadIdx.x;
    int v = (t < SCAN_NBLK) ? blockSums[t] : 0;
    sm[t] = v;
    __syncthreads();
    for (int off = 1; off < 512; off <<= 1) {
        int add = (t >= off) ? sm[t - off] : 0;
        __syncthreads();
        sm[t] += add;
        __syncthreads();
    }
    if (t < SCAN_NBLK) blockSums[t] = sm[t] - v;
}

__global__ void k_scan3(int* __restrict__ rp, const int* __restrict__ blockSums,
                        int* __restrict__ next) {
    int i = blockIdx.x * SCAN_CHUNK + threadIdx.x;
    if (i <= NKEYS) {
        int val = rp[i] + blockSums[blockIdx.x];
        rp[i] = val;
        if (i < NKEYS) next[i] = val;
    }
}

// fill bucketed edge list: (local_col_within_quarter, weight)
__global__ void k_scatter_edges(const int* __restrict__ rows, const int* __restrict__ cols,
                                const float* __restrict__ w,
                                int* __restrict__ next, int2* __restrict__ csr) {
    int i = blockIdx.x * blockDim.x + threadIdx.x;
    int stride = gridDim.x * blockDim.x;
    for (; i < N_EDGES; i += stride) {
        int c = cols[i];
        int q = c / QSZ;
        int key = rows[i] * NQ + q;
        int p = atomicAdd(&next[key], 1);
        csr[p] = make_int2(c - q * QSZ, __float_as_int(w[i]));
    }
}

__device__ __forceinline__ float segsum(const int* __restrict__ rp2,
                                        const int2* __restrict__ csr,
                                        const float* __restrict__ sy,
                                        int row, int q, int j) {
    const int key = row * NQ + q;
    int e = rp2[key] + j;
    const int end = rp2[key + 1];
    float a0 = 0.f, a1 = 0.f;
    for (; e + 4 < end; e += 8) {        // 4 lanes/row, 2-way MLP
        int2 c0 = csr[e];
        int2 c1 = csr[e + 4];
        a0 += __int_as_float(c0.y) * sy[c0.x];
        a1 += __int_as_float(c1.y) * sy[c1.x];
    }
    if (e < end) {
        int2 c = csr[e];
        a0 += __int_as_float(c.y) * sy[c.x];
    }
    return a0 + a1;
}

// Persistent loop. Per iteration: 4x {stage y-quarter to LDS; accumulate}.
// Barrier: per-block arrival stores; block 0 aggregates; 64 replicated epoch
// words (128B apart) polled by 1 thread/block with s_sleep backoff.
__global__ __launch_bounds__(NT) void k_iterate(
    const int*  __restrict__ rp2,
    const int2* __restrict__ csr,
    const float* __restrict__ b_in,
    float* __restrict__ ybuf0,
    float* __restrict__ ybuf1,
    int* __restrict__ arr,
    int* __restrict__ epoch,
    const int* __restrict__ out_idx,
    const float* __restrict__ out_w,
    float* __restrict__ out)
{
    __shared__ float sy[QSZ];            // 100 KB
    const int b = blockIdx.x, t = threadIdx.x;
    const int nb = gridDim.x;
    const int g = t >> 2, j = t & 3;     // 256 groups of 4 lanes
    const int row0 = b * RPB;
    const int row_end = (row0 + RPB < N_NODES) ? row0 + RPB : N_NODES;
    const int r1 = row0 + g;
    const int r2 = row0 + g + 256;

    const float* ycur = ybuf0;
    float* ynext = ybuf1;

    for (int it = 1; it < ITERS; ++it) {
        float acc1 = 0.f, acc2 = 0.f;
        #pragma unroll
        for (int q = 0; q < NQ; ++q) {
            const float4* src = (const float4*)(ycur + q * QSZ);
            #pragma unroll
            for (int i = 0; i < 7; ++i) {
                int idx = t + i * NT;
                if (idx < QSZ / 4) ((float4*)sy)[idx] = src[idx];
            }
            __syncthreads();
            if (r1 < row_end) acc1 += segsum(rp2, csr, sy, r1, q, j);
            if (r2 < row_end) acc2 += segsum(rp2, csr, sy, r2, q, j);
            __syncthreads();             // before overwriting sy
        }
        acc1 += __shfl_xor(acc1, 1); acc1 += __shfl_xor(acc1, 2);
        acc2 += __shfl_xor(acc2, 1); acc2 += __shfl_xor(acc2, 2);
        if (j == 0) {
            if (r1 < row_end) ynext[r1] = mml(b_in[r1] + acc1);
            if (r2 < row_end) ynext[r2] = mml(b_in[r2] + acc2);
        }
        __syncthreads();                 // all stores issued

        // ---- arrive ----
        if (t == 0) {
            __builtin_amdgcn_fence(__ATOMIC_RELEASE, "agent"); // wb dirty L2 (ynext)
            __hip_atomic_store(&arr[b], it, __ATOMIC_RELAXED,
                               __HIP_MEMORY_SCOPE_AGENT);
        }
        // ---- block 0 aggregates, broadcasts to 64 epoch copies ----
        if (b == 0) {
            int done;
            do {
                done = (t < nb) ? (__hip_atomic_load(&arr[t], __ATOMIC_RELAXED,
                                     __HIP_MEMORY_SCOPE_AGENT) >= it) : 1;
                if (!done) __builtin_amdgcn_s_sleep(2);
            } while (__syncthreads_and(done) == 0);
            if (t < NEPOCH)
                __hip_atomic_store(&epoch[t * EPOCH_STRIDE], it, __ATOMIC_RELAXED,
                                   __HIP_MEMORY_SCOPE_AGENT);
        } else {
            if (t == 0) {
                while (__hip_atomic_load(&epoch[(b & (NEPOCH - 1)) * EPOCH_STRIDE],
                         __ATOMIC_RELAXED, __HIP_MEMORY_SCOPE_AGENT) < it)
                    __builtin_amdgcn_s_sleep(8);
            }
            __syncthreads();
        }
        __builtin_amdgcn_fence(__ATOMIC_ACQUIRE, "agent");     // inv L1/L2
        __syncthreads();

        { const float* tmp = ycur; ycur = ynext; ynext = (float*)tmp; }
    }

    if (b == 0 && t < N_OUT) out[t] = out_w[t] * ycur[out_idx[t]];
}

extern "C" void kernel_launch(void* const* d_in, const int* in_sizes, int n_in,
                              void* d_out, int out_size, void* d_ws, size_t ws_size,
                              hipStream_t stream) {
    const float* x      = (const float*)d_in[0];
    const float* in_w   = (const float*)d_in[1];
    const float* rec_w  = (const float*)d_in[2];
    const float* biases = (const float*)d_in[3];
    const float* out_w  = (const float*)d_in[4];
    const int*   in_idx = (const int*)d_in[5];
    const int*   e_rows = (const int*)d_in[6];
    const int*   e_cols = (const int*)d_in[7];
    const int*   out_idx= (const int*)d_in[8];
    float* out = (float*)d_out;

    char* ws = (char*)d_ws;
    float* b_in    = (float*)ws;                       // N
    float* y0      = b_in + N_NODES;                   // N
    float* y1      = y0 + N_NODES;                     // N
    int*   rp2     = (int*)(y1 + N_NODES);             // NKEYS+1 (+pad)
    int*   counts  = rp2 + (NKEYS + 64);               // NKEYS (reused as `next`)
    int*   blockSums = counts + NKEYS;                 // 512
    int*   arr     = blockSums + 512;                  // NB
    int*   epoch   = arr + NB;                         // NEPOCH*EPOCH_STRIDE
    size_t off = (size_t)((char*)(epoch + NEPOCH * EPOCH_STRIDE) - ws);
    off = (off + 15) & ~(size_t)15;
    int2* csr = (int2*)(ws + off);                     // N_EDGES int2 (25.6 MB)

    hipMemsetAsync(counts, 0, NKEYS * sizeof(int), stream);
    hipMemsetAsync(arr, 0, (NB + NEPOCH * EPOCH_STRIDE) * sizeof(int), stream);

    k_binit<<<391, 256, 0, stream>>>(biases, b_in);
    k_scatter_in<<<1, 128, 0, stream>>>(x, in_w, in_idx, biases, b_in);
    k_y0<<<391, 256, 0, stream>>>(b_in, y0);

    k_hist<<<1024, 256, 0, stream>>>(e_rows, e_cols, counts);
    k_scan1<<<SCAN_NBLK, SCAN_CHUNK, 0, stream>>>(counts, rp2, blockSums);
    k_scan2<<<1, 512, 0, stream>>>(blockSums);
    k_scan3<<<SCAN_NBLK, SCAN_CHUNK, 0, stream>>>(rp2, blockSums, counts); // counts = next
    k_scatter_edges<<<1024, 256, 0, stream>>>(e_rows, e_cols, rec_w, counts, csr);

    int*   rp_a   = rp2;
    int2*  csr_a  = csr;
    float* bin_a  = b_in;
    float* y0_a   = y0;
    float* y1_a   = y1;
    int*   arr_a  = arr;
    int*   ep_a   = epoch;
    const int*   oidx_a = out_idx;
    const float* ow_a   = out_w;
    float* out_a  = out;
    void* args[] = { &rp_a, &csr_a, &bin_a, &y0_a, &y1_a, &arr_a, &ep_a,
                     &oidx_a, &ow_a, &out_a };
    hipLaunchCooperativeKernel((void*)k_iterate, dim3(NB), dim3(NT),
                               args, 0, stream);
}

// Round 4
// 3112.135 us; speedup vs baseline: 4.8077x; 2.5203x over previous
//
#include <hip/hip_runtime.h>

#define N_NODES 100000
#define N_EDGES 3200000
#define N_IN    128
#define N_OUT   64
#define ITERS   150
#define LEAK    0.01f

#define NB      256            // 1 block per CU (forced by 100KB LDS)
#define NT      1024
#define RPB     391            // ceil(N_NODES / NB) rows per block
#define NQ      4              // column quarters
#define QSZ     25000          // columns per quarter (100KB of y in LDS)
#define NKEYS   (N_NODES * NQ) // (row, quarter) buckets
#define SCAN_CHUNK 1024
#define SCAN_NBLK  391         // 391*1024 >= NKEYS+1
#define NEPOCH  64
#define EPOCH_STRIDE 32        // ints -> 128B between epoch copies
#define YSTR    100096         // y buffer stride (multiple of 64 floats)

__device__ __forceinline__ float mml(float v) {
    v = (v < 0.0f) ? v * LEAK : v;
    if (v > 0.5f) v = 1.0f - 0.25f / v;
    return v;
}

__global__ void k_binit(const float* __restrict__ biases, float* __restrict__ b_in) {
    int i = blockIdx.x * blockDim.x + threadIdx.x;
    if (i < N_NODES) b_in[i] = biases[i];
}

// node_in.at[in_indices].set(in_w * x) -> last-write-wins for duplicates
__global__ void k_scatter_in(const float* __restrict__ x,
                             const float* __restrict__ in_w,
                             const int*   __restrict__ in_idx,
                             const float* __restrict__ biases,
                             float* __restrict__ b_in) {
    int k = threadIdx.x;
    if (k < N_IN) {
        int idx = in_idx[k];
        bool last = true;
        for (int j = k + 1; j < N_IN; ++j)
            if (in_idx[j] == idx) { last = false; break; }
        if (last) b_in[idx] = biases[idx] + in_w[k] * x[k];
    }
}

// y0 = act(0 + b_in)   (first reference iteration: A @ 0 == 0)
__global__ void k_y0(const float* __restrict__ b_in, float* __restrict__ y0) {
    int i = blockIdx.x * blockDim.x + threadIdx.x;
    if (i < N_NODES) y0[i] = mml(b_in[i]);
}

// histogram over (row, col-quarter) buckets
__global__ void k_hist(const int* __restrict__ rows, const int* __restrict__ cols,
                       int* __restrict__ counts) {
    int i = blockIdx.x * blockDim.x + threadIdx.x;
    int stride = gridDim.x * blockDim.x;
    for (; i < N_EDGES; i += stride) {
        int key = rows[i] * NQ + cols[i] / QSZ;
        atomicAdd(&counts[key], 1);
    }
}

__global__ void k_scan1(const int* __restrict__ counts, int* __restrict__ rp,
                        int* __restrict__ blockSums) {
    __shared__ int sm[SCAN_CHUNK];
    int t = threadIdx.x;
    int i = blockIdx.x * SCAN_CHUNK + t;
    int v = (i < NKEYS) ? counts[i] : 0;
    sm[t] = v;
    __syncthreads();
    for (int off = 1; off < SCAN_CHUNK; off <<= 1) {
        int add = (t >= off) ? sm[t - off] : 0;
        __syncthreads();
        sm[t] += add;
        __syncthreads();
    }
    if (i <= NKEYS) rp[i] = sm[t] - v;
    if (t == SCAN_CHUNK - 1) blockSums[blockIdx.x] = sm[t];
}

__global__ void k_scan2(int* __restrict__ blockSums) {
    __shared__ int sm[512];
    int t = threadIdx.x;
    int v = (t < SCAN_NBLK) ? blockSums[t] : 0;
    sm[t] = v;
    __syncthreads();
    for (int off = 1; off < 512; off <<= 1) {
        int add = (t >= off) ? sm[t - off] : 0;
        __syncthreads();
        sm[t] += add;
        __syncthreads();
    }
    if (t < SCAN_NBLK) blockSums[t] = sm[t] - v;
}

__global__ void k_scan3(int* __restrict__ rp, const int* __restrict__ blockSums,
                        int* __restrict__ next) {
    int i = blockIdx.x * SCAN_CHUNK + threadIdx.x;
    if (i <= NKEYS) {
        int val = rp[i] + blockSums[blockIdx.x];
        rp[i] = val;
        if (i < NKEYS) next[i] = val;
    }
}

// fill bucketed edge list: (local_col_within_quarter, weight)
__global__ void k_scatter_edges(const int* __restrict__ rows, const int* __restrict__ cols,
                                const float* __restrict__ w,
                                int* __restrict__ next, int2* __restrict__ csr) {
    int i = blockIdx.x * blockDim.x + threadIdx.x;
    int stride = gridDim.x * blockDim.x;
    for (; i < N_EDGES; i += stride) {
        int c = cols[i];
        int q = c / QSZ;
        int key = rows[i] * NQ + q;
        int p = atomicAdd(&next[key], 1);
        csr[p] = make_int2(c - q * QSZ, __float_as_int(w[i]));
    }
}

__device__ __forceinline__ float segsum(const int* __restrict__ rp2,
                                        const int2* __restrict__ csr,
                                        const float* __restrict__ sy,
                                        int row, int q, int j) {
    const int key = row * NQ + q;
    int e = rp2[key] + j;
    const int end = rp2[key + 1];
    float a0 = 0.f, a1 = 0.f;
    for (; e + 4 < end; e += 8) {        // 4 lanes/row, 2-way MLP
        int2 c0 = csr[e];
        int2 c1 = csr[e + 4];
        a0 += __int_as_float(c0.y) * sy[c0.x];
        a1 += __int_as_float(c1.y) * sy[c1.x];
    }
    if (e < end) {
        int2 c = csr[e];
        a0 += __int_as_float(c.y) * sy[c.x];
    }
    return a0 + a1;
}

// Persistent loop, NO cache-invalidating fences in steady state:
//  - y writes: agent-scope (L2-bypassing) stores straight to MALL
//  - y reads:  nbuf=150 rotating buffers -> always-cold L2 lines (normal
//    coalesced loads, L2-shared within XCD), or sc1 scalar loads if nbuf=2
//  - CSR/rp2/b_in stay L2-resident across all iterations (never invalidated)
//  - barrier: per-block arrival stores; block0 wave0 aggregates (64 lanes x
//    4 slots); 64 replicated epoch words polled 1 thread/block with s_sleep
__global__ __launch_bounds__(NT) void k_iterate(
    const int*  __restrict__ rp2,
    const int2* __restrict__ csr,
    const float* __restrict__ b_in,
    float* __restrict__ ybufs,
    int* __restrict__ arr,
    int* __restrict__ epoch,
    const int* __restrict__ out_idx,
    const float* __restrict__ out_w,
    float* __restrict__ out,
    int nbuf, int sc1mode)
{
    __shared__ float sy[QSZ];            // 100 KB
    const int b = blockIdx.x, t = threadIdx.x;
    const int nb = gridDim.x;
    const int g = t >> 2, j = t & 3;     // 256 groups of 4 lanes
    const int row0 = b * RPB;
    const int row_end = (row0 + RPB < N_NODES) ? row0 + RPB : N_NODES;
    const int r1 = row0 + g;
    const int r2 = row0 + g + 256;

    for (int it = 1; it < ITERS; ++it) {
        const float* ysrc = ybufs + (size_t)((it - 1) % nbuf) * YSTR;
        float*       ydst = ybufs + (size_t)(it % nbuf) * YSTR;
        float acc1 = 0.f, acc2 = 0.f;
        #pragma unroll
        for (int q = 0; q < NQ; ++q) {
            if (!sc1mode) {
                const float4* src = (const float4*)(ysrc + q * QSZ);
                #pragma unroll
                for (int i = 0; i < 7; ++i) {
                    int idx = t + i * NT;
                    if (idx < QSZ / 4) ((float4*)sy)[idx] = src[idx];
                }
            } else {
                const float* src = ysrc + q * QSZ;
                #pragma unroll
                for (int i = 0; i < 25; ++i) {
                    int idx = t + i * NT;
                    if (idx < QSZ)
                        sy[idx] = __hip_atomic_load(&src[idx], __ATOMIC_RELAXED,
                                                    __HIP_MEMORY_SCOPE_AGENT);
                }
            }
            __syncthreads();
            if (r1 < row_end) acc1 += segsum(rp2, csr, sy, r1, q, j);
            if (r2 < row_end) acc2 += segsum(rp2, csr, sy, r2, q, j);
            __syncthreads();             // before overwriting sy
        }
        acc1 += __shfl_xor(acc1, 1); acc1 += __shfl_xor(acc1, 2);
        acc2 += __shfl_xor(acc2, 1); acc2 += __shfl_xor(acc2, 2);
        if (j == 0) {
            if (r1 < row_end)
                __hip_atomic_store(&ydst[r1], mml(b_in[r1] + acc1),
                                   __ATOMIC_RELAXED, __HIP_MEMORY_SCOPE_AGENT);
            if (r2 < row_end)
                __hip_atomic_store(&ydst[r2], mml(b_in[r2] + acc2),
                                   __ATOMIC_RELAXED, __HIP_MEMORY_SCOPE_AGENT);
        }
        // each wave drains its own vmem (vmcnt(0) before s_barrier) -> all
        // sc1 y-stores are MALL-visible once every wave passes this barrier
        __syncthreads();

        // ---- arrive ----
        if (t == 0)
            __hip_atomic_store(&arr[b], it, __ATOMIC_RELEASE,
                               __HIP_MEMORY_SCOPE_AGENT);
        // ---- block0 wave0 aggregates; others poll replicated epoch ----
        if (b == 0) {
            if (t < 64) {
                int ok;
                do {
                    ok = 1;
                    #pragma unroll
                    for (int k = 0; k < 4; ++k) {
                        int bb = t + k * 64;
                        if (bb < nb)
                            ok &= (__hip_atomic_load(&arr[bb], __ATOMIC_RELAXED,
                                     __HIP_MEMORY_SCOPE_AGENT) >= it);
                    }
                    if (!ok) __builtin_amdgcn_s_sleep(1);
                } while (!__all(ok));
                __hip_atomic_store(&epoch[t * EPOCH_STRIDE], it,
                                   __ATOMIC_RELAXED, __HIP_MEMORY_SCOPE_AGENT);
            }
            __syncthreads();
        } else {
            if (t == 0) {
                while (__hip_atomic_load(&epoch[(b & (NEPOCH - 1)) * EPOCH_STRIDE],
                         __ATOMIC_RELAXED, __HIP_MEMORY_SCOPE_AGENT) < it)
                    __builtin_amdgcn_s_sleep(2);
            }
            __syncthreads();
        }
        asm volatile("" ::: "memory");   // no HW fence needed: no stale lines
    }

    if (b == 0 && t < N_OUT) {
        const float* yfin = ybufs + (size_t)((ITERS - 1) % nbuf) * YSTR;
        out[t] = out_w[t] * __hip_atomic_load(&yfin[out_idx[t]],
                   __ATOMIC_RELAXED, __HIP_MEMORY_SCOPE_AGENT);
    }
}

extern "C" void kernel_launch(void* const* d_in, const int* in_sizes, int n_in,
                              void* d_out, int out_size, void* d_ws, size_t ws_size,
                              hipStream_t stream) {
    const float* x      = (const float*)d_in[0];
    const float* in_w   = (const float*)d_in[1];
    const float* rec_w  = (const float*)d_in[2];
    const float* biases = (const float*)d_in[3];
    const float* out_w  = (const float*)d_in[4];
    const int*   in_idx = (const int*)d_in[5];
    const int*   e_rows = (const int*)d_in[6];
    const int*   e_cols = (const int*)d_in[7];
    const int*   out_idx= (const int*)d_in[8];
    float* out = (float*)d_out;

    char* ws = (char*)d_ws;
    float* b_in    = (float*)ws;                       // N
    int*   rp2     = (int*)(b_in + N_NODES);           // NKEYS+1 (+pad)
    int*   counts  = rp2 + (NKEYS + 64);               // NKEYS (reused as `next`)
    int*   blockSums = counts + NKEYS;                 // 512
    int*   arr     = blockSums + 512;                  // NB
    int*   epoch   = arr + NB;                         // NEPOCH*EPOCH_STRIDE
    size_t off = (size_t)((char*)(epoch + NEPOCH * EPOCH_STRIDE) - ws);
    off = (off + 255) & ~(size_t)255;
    int2* csr = (int2*)(ws + off);                     // N_EDGES int2 (25.6 MB)
    size_t off2 = off + (size_t)N_EDGES * sizeof(int2);
    off2 = (off2 + 255) & ~(size_t)255;
    float* ybufs = (float*)(ws + off2);                // nbuf * YSTR floats

    size_t fullA = off2 + (size_t)150 * YSTR * sizeof(float);
    int nbuf, sc1mode;
    if (ws_size >= fullA) { nbuf = 150; sc1mode = 0; }
    else                  { nbuf = 2;   sc1mode = 1; }

    hipMemsetAsync(counts, 0, NKEYS * sizeof(int), stream);
    hipMemsetAsync(arr, 0, (NB + NEPOCH * EPOCH_STRIDE) * sizeof(int), stream);

    k_binit<<<391, 256, 0, stream>>>(biases, b_in);
    k_scatter_in<<<1, 128, 0, stream>>>(x, in_w, in_idx, biases, b_in);
    k_y0<<<391, 256, 0, stream>>>(b_in, ybufs);        // y buffer 0

    k_hist<<<1024, 256, 0, stream>>>(e_rows, e_cols, counts);
    k_scan1<<<SCAN_NBLK, SCAN_CHUNK, 0, stream>>>(counts, rp2, blockSums);
    k_scan2<<<1, 512, 0, stream>>>(blockSums);
    k_scan3<<<SCAN_NBLK, SCAN_CHUNK, 0, stream>>>(rp2, blockSums, counts); // counts = next
    k_scatter_edges<<<1024, 256, 0, stream>>>(e_rows, e_cols, rec_w, counts, csr);

    int*   rp_a   = rp2;
    int2*  csr_a  = csr;
    float* bin_a  = b_in;
    float* yb_a   = ybufs;
    int*   arr_a  = arr;
    int*   ep_a   = epoch;
    const int*   oidx_a = out_idx;
    const float* ow_a   = out_w;
    float* out_a  = out;
    void* args[] = { &rp_a, &csr_a, &bin_a, &yb_a, &arr_a, &ep_a,
                     &oidx_a, &ow_a, &out_a, &nbuf, &sc1mode };
    hipLaunchCooperativeKernel((void*)k_iterate, dim3(NB), dim3(NT),
                               args, 0, stream);
}